// Round 9
// baseline (748.561 us; speedup 1.0000x reference)
//
#include <hip/hip_runtime.h>
#include <cstddef>

#define NB 256   // batch
#define NT 512   // time
#define ND 128   // input dim
#define NH 128   // hidden
#define NG 512   // 4*H
#define NM (NB * NT)     // 131072 rows of the input GEMM (m' = t*NB + b)
#define NMP (NM + 64)    // padded G stride (f16 elems): breaks L2 set aliasing
#define LBLK 16          // batch rows per k_lstm block

constexpr float F_EPS  = 1e-7f;
constexpr float F_TEMP = 0.1f;

typedef _Float16 h4_t __attribute__((ext_vector_type(4)));
typedef _Float16 h8_t __attribute__((ext_vector_type(8)));
typedef float    fx4  __attribute__((ext_vector_type(4)));

__device__ __forceinline__ float fexp2(float x) {
#if defined(__has_builtin)
#  if __has_builtin(__builtin_amdgcn_exp2f)
    return __builtin_amdgcn_exp2f(x);
#  else
    return exp2f(x);
#  endif
#else
    return exp2f(x);
#endif
}
__device__ __forceinline__ float frcp(float x) {
#if defined(__has_builtin)
#  if __has_builtin(__builtin_amdgcn_rcpf)
    return __builtin_amdgcn_rcpf(x);
#  else
    return 1.0f / x;
#  endif
#else
    return 1.0f / x;
#endif
}
__device__ __forceinline__ float fsig(float x) {
    return frcp(1.0f + fexp2(x * -1.44269504088896f));
}
__device__ __forceinline__ float ftanh(float x) {
    return 1.0f - 2.0f * frcp(1.0f + fexp2(x * 2.885390081777927f));
}
__device__ __forceinline__ float sig(float x) { return 1.0f / (1.0f + expf(-x)); }

// LDS-ordering-only barrier: does NOT drain vmcnt (global loads/stores stay in
// flight). lgkmcnt(0) orders our ds ops before the barrier; sched_barrier pins
// it (rule #18).
__device__ __forceinline__ void bar_lds() {
    asm volatile("s_waitcnt lgkmcnt(0)" ::: "memory");
    __builtin_amdgcn_sched_barrier(0);
    __builtin_amdgcn_s_barrier();
}

// ---------------- kernel 1: weight f16 conversion + w^2 sums + concrete masks -------
__global__ __launch_bounds__(256) void k_convert(const float* __restrict__ wih,
        const float* __restrict__ whh, const float* __restrict__ pl,
        const float* __restrict__ plr, const float* __restrict__ unif_x,
        const float* __restrict__ unif_h, _Float16* __restrict__ wih_h,
        _Float16* __restrict__ whh_h, _Float16* __restrict__ mask_x,
        _Float16* __restrict__ mask_h, float* __restrict__ partial) {
    int i = blockIdx.x * 256 + threadIdx.x;    // float4 index, 16384 total
    float4 a = ((const float4*)wih)[i];
    float4 b = ((const float4*)whh)[i];
    h4_t ah, bh;
    ah[0] = (_Float16)a.x; ah[1] = (_Float16)a.y; ah[2] = (_Float16)a.z; ah[3] = (_Float16)a.w;
    bh[0] = (_Float16)b.x; bh[1] = (_Float16)b.y; bh[2] = (_Float16)b.z; bh[3] = (_Float16)b.w;
    *(h4_t*)(wih_h + 4 * (size_t)i) = ah;
    *(h4_t*)(whh_h + 4 * (size_t)i) = bh;
    float sk = a.x * a.x + a.y * a.y + a.z * a.z + a.w * a.w;
    float sr = b.x * b.x + b.y * b.y + b.z * b.z + b.w * b.w;
    for (int off = 32; off; off >>= 1) {
        sk += __shfl_down(sk, off);
        sr += __shfl_down(sr, off);
    }
    if ((threadIdx.x & 63) == 0) {
        atomicAdd(partial + 0, sk);
        atomicAdd(partial + 1, sr);
    }
    // concrete-dropout masks: threads 0..8191 -> mask_x, 8192..16383 -> mask_h
    float p;
    const float* up;
    _Float16* mp;
    int mi;
    if (i < 8192) { p = sig(pl[0]);  up = unif_x; mp = mask_x; mi = i; }
    else          { p = sig(plr[0]); up = unif_h; mp = mask_h; mi = i - 8192; }
    float4 u = ((const float4*)up)[mi];
    float base = logf(p + F_EPS) - logf(1.f - p + F_EPS);
    float inv  = 1.f / (1.f - p);
    h4_t m4;
    {
        float uu[4] = {u.x, u.y, u.z, u.w};
#pragma unroll
        for (int e = 0; e < 4; ++e) {
            float lg = base + logf(uu[e] + F_EPS) - logf(1.f - uu[e] + F_EPS);
            float mk = 1.f - sig(lg / F_TEMP);
            m4[e] = (_Float16)(mk * inv);
        }
    }
    *(h4_t*)(mp + 4 * (size_t)mi) = m4;
}

// ---------------- kernel 1b: finalize scalar regularization outputs ----------------
__global__ void k_tail(const float* __restrict__ bih, const float* __restrict__ bhh,
                       const float* __restrict__ pl, const float* __restrict__ plr,
                       const float* __restrict__ partial, float* __restrict__ out_tail) {
    __shared__ float red[8];
    int t = threadIdx.x;  // 512 threads
    float v = bih[t], w2 = bhh[t];
    float sb = v * v + w2 * w2;
    for (int off = 32; off; off >>= 1) sb += __shfl_down(sb, off);
    int wid = t >> 6, lane = t & 63;
    if (lane == 0) red[wid] = sb;
    __syncthreads();
    if (t == 0) {
        float SB = 0.f;
        for (int i = 0; i < 8; i++) SB += red[i];
        float SK = partial[0], SR = partial[1];
        float p  = sig(pl[0]);
        float pr = sig(plr[0]);
        float wr = 1e-6f * (SK / (1.f - p) + SR / (1.f - pr));
        float br = 1e-6f * SB;
        float ek = p * logf(p) + (1.f - p) * logf(1.f - p);
        float er = pr * logf(pr) + (1.f - pr) * logf(1.f - pr);
        float dr = 1e-5f * ((float)ND * ek + (float)NH * er);
        out_tail[0] = wr + br + dr;
        out_tail[1] = p;
        out_tail[2] = pr;
    }
}

// ---------------- kernel 2: f16 MFMA input GEMM ----------------
// G[j][m'] with m' = t*NB + b (TIME-MAJOR). A-tile rows = 128 batches at fixed
// t; mask from precomputed f16 table. Epilogue identical to the proven one.
__global__ __launch_bounds__(256, 2) void k_gemm(const float* __restrict__ x,
        const _Float16* __restrict__ wih_h, const float* __restrict__ bih,
        const float* __restrict__ bhh, const _Float16* __restrict__ mask_x,
        _Float16* __restrict__ Gp) {
    __shared__ _Float16 Alds[128 * 128];
    __shared__ _Float16 Wlds[128 * 128];
    __shared__ float bsum[128];
    int t  = threadIdx.x;
    int m0 = blockIdx.x * 128;           // m' block
    int j0 = blockIdx.y * 128;           // gate-col block
    int tg  = blockIdx.x >> 1;           // timestep of this tile
    int b0g = (blockIdx.x & 1) * 128;    // batch base of this tile

    if (t < 128) bsum[t] = bih[j0 + t] + bhh[j0 + t];
    __syncthreads();

#pragma unroll
    for (int i = 0; i < 8; i++) {
        int s   = i * 256 + t;
        int row = s >> 4;                 // 0..127 (batch-local)
        int s16 = s & 15;                 // 16B slot within row
        int bb  = b0g + row;
        const float4* xp = (const float4*)(x + ((size_t)bb * NT + tg) * ND + s16 * 8);
        float4 v0 = xp[0], v1 = xp[1];
        h8_t mk = *(const h8_t*)(mask_x + (size_t)bb * ND + s16 * 8);
        h8_t hv;
        hv[0] = (_Float16)(v0.x * (float)mk[0]); hv[1] = (_Float16)(v0.y * (float)mk[1]);
        hv[2] = (_Float16)(v0.z * (float)mk[2]); hv[3] = (_Float16)(v0.w * (float)mk[3]);
        hv[4] = (_Float16)(v1.x * (float)mk[4]); hv[5] = (_Float16)(v1.y * (float)mk[5]);
        hv[6] = (_Float16)(v1.z * (float)mk[6]); hv[7] = (_Float16)(v1.w * (float)mk[7]);
        *(h8_t*)(&Alds[(size_t)row * 128 + ((s16 ^ (row & 7)) << 3)]) = hv;
        h8_t wv = *(const h8_t*)(wih_h + (size_t)(j0 + row) * ND + s16 * 8);
        *(h8_t*)(&Wlds[(size_t)row * 128 + ((s16 ^ (row & 7)) << 3)]) = wv;
    }
    __syncthreads();

    int w  = t >> 6, l = t & 63;
    int lr = l & 15, lg = l >> 4;
    fx4 acc[2][8] = {};
#pragma unroll
    for (int kk = 0; kk < 4; kk++) {
        h8_t af[2], bf[8];
#pragma unroll
        for (int mt = 0; mt < 2; mt++) {
            int r = 32 * w + 16 * mt + lr;
            af[mt] = *(const h8_t*)(&Alds[(size_t)r * 128 + (((4 * kk + lg) ^ (r & 7)) << 3)]);
        }
#pragma unroll
        for (int nt = 0; nt < 8; nt++) {
            int r = 16 * nt + lr;
            bf[nt] = *(const h8_t*)(&Wlds[(size_t)r * 128 + (((4 * kk + lg) ^ (r & 7)) << 3)]);
        }
#pragma unroll
        for (int mt = 0; mt < 2; mt++)
#pragma unroll
            for (int nt = 0; nt < 8; nt++)
                acc[mt][nt] = __builtin_amdgcn_mfma_f32_16x16x32_f16(af[mt], bf[nt], acc[mt][nt], 0, 0, 0);
    }

#pragma unroll
    for (int mt = 0; mt < 2; mt++)
#pragma unroll
        for (int nt = 0; nt < 8; nt++) {
            int j = j0 + 16 * nt + lr;
            int m = m0 + 32 * w + 16 * mt + 4 * lg;
            float bv = bsum[16 * nt + lr];
            h4_t o;
#pragma unroll
            for (int q = 0; q < 4; q++) o[q] = (_Float16)(acc[mt][nt][q] + bv);
            *(h4_t*)(Gp + (size_t)j * NMP + m) = o;
        }
}

// ---------------- kernel 3: MFMA recurrence ----------------
// 16 blocks x 16 batch rows, 512 threads (8 waves). Wave wv owns hidden units
// [16wv,16wv+16); its 4 n-tiles are the 4 GATES of those units -> after MFMA
// each lane holds i,f,g,o of (batch m=(l>>4)*4+reg, unit u=16wv+(l&15)) IN-LANE
// (C layout verified by k_gemm). W_hh lives in B-fragments: 16 h8 = 64 VGPRs,
// pinned. hd[2][16][128] f16, XOR-swizzled (byte ^= (m&7)<<4): A-frag
// ds_read_b128 is 2-way-conflict-free. One LDS-only barrier/step. G prefetched
// 1 step ahead; time-major layout makes the per-step slice contiguous; blocks
// XCD-paired (bc=(i&7)*2+(i>>3)) so adjacent batch chunks share an L2.
__global__ __launch_bounds__(512, 1)
void k_lstm(const _Float16* __restrict__ Gp, const _Float16* __restrict__ whh_h,
            const _Float16* __restrict__ maskh,
            float* __restrict__ xout, float* __restrict__ hlast) {
    __shared__ _Float16 hd[2][LBLK * 128];
    int tid = threadIdx.x;
    int l   = tid & 63;
    int wv  = tid >> 6;            // 0..7
    int lr  = l & 15;              // A-row (batch) for reads / C-col (unit)
    int lq  = l >> 4;              // quarter
    int bc  = ((blockIdx.x & 7) << 1) | (blockIdx.x >> 3);   // XCD pairing
    int b0  = bc * LBLK;
    int u   = wv * 16 + lr;        // hidden unit owned

    // B-fragments: bf[g][kk] = W_hh[g*128+u][kk*32 + lq*8 .. +8)
    h8_t bf[4][4];
#pragma unroll
    for (int g = 0; g < 4; ++g)
#pragma unroll
        for (int kk = 0; kk < 4; ++kk)
            bf[g][kk] = *(const h8_t*)(whh_h + (size_t)(g * 128 + u) * NH + kk * 32 + lq * 8);

    float msk[4], c4[4], hl[4];
#pragma unroll
    for (int r = 0; r < 4; ++r) {
        msk[r] = (float)maskh[(size_t)(b0 + lq * 4 + r) * NH + u];
        c4[r] = 0.f; hl[r] = 0.f;
    }

    // G streams: row j = g*128+u, col t*NB + (b0 + lq*4 .. +4) -> h4 per step
    const _Float16* gp0 = Gp + (size_t)(0 * 128 + u) * NMP + b0 + lq * 4;
    const _Float16* gp1 = Gp + (size_t)(1 * 128 + u) * NMP + b0 + lq * 4;
    const _Float16* gp2 = Gp + (size_t)(2 * 128 + u) * NMP + b0 + lq * 4;
    const _Float16* gp3 = Gp + (size_t)(3 * 128 + u) * NMP + b0 + lq * 4;
    float* xo0 = xout + (size_t)(b0 + lq * 4 + 0) * NT * NH + u;
    float* xo1 = xout + (size_t)(b0 + lq * 4 + 1) * NT * NH + u;
    float* xo2 = xout + (size_t)(b0 + lq * 4 + 2) * NT * NH + u;
    float* xo3 = xout + (size_t)(b0 + lq * 4 + 3) * NT * NH + u;

    // zero-init hd parity 0 (h0 state)
    {
        char* h0 = (char*)&hd[0][0];
#pragma unroll
        for (int r = 0; r < 4; ++r) {
            int m = lq * 4 + r;
            *(_Float16*)(h0 + m * 256 + ((2 * u) ^ ((m & 7) << 4))) = (_Float16)0.f;
        }
    }
    __syncthreads();

    h4_t gA0 = *(const h4_t*)(gp0);
    h4_t gA1 = *(const h4_t*)(gp1);
    h4_t gA2 = *(const h4_t*)(gp2);
    h4_t gA3 = *(const h4_t*)(gp3);

    for (int t = 0; t < NT; ++t) {
        // pin B-frags (prevent remat/spill of W_hh)
#pragma unroll
        for (int g = 0; g < 4; ++g)
#pragma unroll
            for (int kk = 0; kk < 4; ++kk) asm volatile("" : "+v"(bf[g][kk]));
        h4_t nA0 = gA0, nA1 = gA1, nA2 = gA2, nA3 = gA3;
        if (t + 1 < NT) {   // prefetch next step's G (in flight across barrier)
            nA0 = *(const h4_t*)(gp0 + (size_t)(t + 1) * NB);
            nA1 = *(const h4_t*)(gp1 + (size_t)(t + 1) * NB);
            nA2 = *(const h4_t*)(gp2 + (size_t)(t + 1) * NB);
            nA3 = *(const h4_t*)(gp3 + (size_t)(t + 1) * NB);
        }
        const char* hb = (const char*)&hd[t & 1][0];
        fx4 a0 = {0.f, 0.f, 0.f, 0.f}, a1 = a0, a2 = a0, a3 = a0;
#pragma unroll
        for (int kk = 0; kk < 4; ++kk) {
            h8_t af = *(const h8_t*)(hb + lr * 256 + ((kk * 64 + lq * 16) ^ ((lr & 7) << 4)));
            a0 = __builtin_amdgcn_mfma_f32_16x16x32_f16(af, bf[0][kk], a0, 0, 0, 0);
            a1 = __builtin_amdgcn_mfma_f32_16x16x32_f16(af, bf[1][kk], a1, 0, 0, 0);
            a2 = __builtin_amdgcn_mfma_f32_16x16x32_f16(af, bf[2][kk], a2, 0, 0, 0);
            a3 = __builtin_amdgcn_mfma_f32_16x16x32_f16(af, bf[3][kk], a3, 0, 0, 0);
        }
        char* hw = (char*)&hd[(t & 1) ^ 1][0];
#pragma unroll
        for (int r = 0; r < 4; ++r) {
            float si = a0[r] + (float)gA0[r];
            float sf = a1[r] + (float)gA1[r];
            float sg = a2[r] + (float)gA2[r];
            float so = a3[r] + (float)gA3[r];
            float iv = fsig(si), fv = fsig(sf);
            float gv = ftanh(sg), ov = fsig(so);
            c4[r] = fv * c4[r] + iv * gv;
            float h = ov * ftanh(c4[r]);
            hl[r] = h;
            int m = lq * 4 + r;
            *(_Float16*)(hw + m * 256 + ((2 * u) ^ ((m & 7) << 4))) = (_Float16)(h * msk[r]);
        }
        xo0[(size_t)t * NH] = hl[0];   // vmem stores: never drained by bar_lds
        xo1[(size_t)t * NH] = hl[1];
        xo2[(size_t)t * NH] = hl[2];
        xo3[(size_t)t * NH] = hl[3];
        gA0 = nA0; gA1 = nA1; gA2 = nA2; gA3 = nA3;
        bar_lds();   // hd writes visible; next step reads other parity
    }
#pragma unroll
    for (int r = 0; r < 4; ++r)
        hlast[(size_t)(b0 + lq * 4 + r) * NH + u] = hl[r];
}

extern "C" void kernel_launch(void* const* d_in, const int* in_sizes, int n_in,
                              void* d_out, int out_size, void* d_ws, size_t ws_size,
                              hipStream_t stream) {
    const float* x   = (const float*)d_in[0];
    const float* wih = (const float*)d_in[1];
    const float* whh = (const float*)d_in[2];
    const float* bih = (const float*)d_in[3];
    const float* bhh = (const float*)d_in[4];
    const float* pl  = (const float*)d_in[5];
    const float* plr = (const float*)d_in[6];
    const float* ux  = (const float*)d_in[7];
    const float* uh  = (const float*)d_in[8];

    float* out   = (float*)d_out;
    float* xout  = out;                                 // [B,T,H]
    float* hlast = out + (size_t)NB * NT * NH;          // [B,H]
    float* tail  = hlast + (size_t)NB * NH;             // reg, p, p_rec

    _Float16* G      = (_Float16*)d_ws;                 // [NG][NMP] f16
    _Float16* wih_h  = G + (size_t)NG * NMP;
    _Float16* whh_h  = wih_h + (size_t)NG * ND;
    _Float16* mask_x = whh_h + (size_t)NG * NH;         // [NB][ND] f16 (incl /(1-p))
    _Float16* mask_h = mask_x + (size_t)NB * ND;        // [NB][NH] f16 (incl /(1-pr))
    float*    partial = (float*)(mask_h + (size_t)NB * NH);   // 2 floats

    hipMemsetAsync(partial, 0, 2 * sizeof(float), stream);

    k_convert<<<64, 256, 0, stream>>>(wih, whh, pl, plr, ux, uh,
                                      wih_h, whh_h, mask_x, mask_h, partial);

    dim3 gg(NM / 128, NG / 128);
    k_gemm<<<gg, 256, 0, stream>>>(x, wih_h, bih, bhh, mask_x, G);

    k_tail<<<1, 512, 0, stream>>>(bih, bhh, pl, plr, partial, tail);

    k_lstm<<<NB / LBLK, 512, 0, stream>>>(G, whh_h, mask_h, xout, hlast);
}

// Round 10
// 557.530 us; speedup vs baseline: 1.3426x; 1.3426x over previous
//
#include <hip/hip_runtime.h>
#include <cstddef>

#define NB 256   // batch
#define NT 512   // time
#define ND 128   // input dim
#define NH 128   // hidden
#define NG 512   // 4*H
#define NM (NB * NT)     // total input-GEMM rows (m' = t*NB + b)
#define NMP (NM + 64)    // legacy sizing constant for ws layout (G fits under NG*NMP)
#define LBLK 16          // batch rows per k_lstm block
#define TSTR ((size_t)16 * 512 * 16)   // G elems per timestep (16 chunks x 512 j x 16 b)

constexpr float F_EPS  = 1e-7f;
constexpr float F_TEMP = 0.1f;

typedef _Float16 h4_t __attribute__((ext_vector_type(4)));
typedef _Float16 h8_t __attribute__((ext_vector_type(8)));
typedef float    fx4  __attribute__((ext_vector_type(4)));

__device__ __forceinline__ float fexp2(float x) {
#if defined(__has_builtin)
#  if __has_builtin(__builtin_amdgcn_exp2f)
    return __builtin_amdgcn_exp2f(x);
#  else
    return exp2f(x);
#  endif
#else
    return exp2f(x);
#endif
}
__device__ __forceinline__ float frcp(float x) {
#if defined(__has_builtin)
#  if __has_builtin(__builtin_amdgcn_rcpf)
    return __builtin_amdgcn_rcpf(x);
#  else
    return 1.0f / x;
#  endif
#else
    return 1.0f / x;
#endif
}
__device__ __forceinline__ float fsig(float x) {
    return frcp(1.0f + fexp2(x * -1.44269504088896f));
}
__device__ __forceinline__ float ftanh(float x) {
    return 1.0f - 2.0f * frcp(1.0f + fexp2(x * 2.885390081777927f));
}
__device__ __forceinline__ float sig(float x) { return 1.0f / (1.0f + expf(-x)); }

// LDS-ordering-only barrier: does NOT drain vmcnt (global loads/stores stay in
// flight). lgkmcnt(0) orders our ds ops before the barrier; sched_barrier pins
// it (rule #18).
__device__ __forceinline__ void bar_lds() {
    asm volatile("s_waitcnt lgkmcnt(0)" ::: "memory");
    __builtin_amdgcn_sched_barrier(0);
    __builtin_amdgcn_s_barrier();
}

// ---------------- kernel 1: weight f16 conversion + w^2 sums + concrete masks -------
__global__ __launch_bounds__(256) void k_convert(const float* __restrict__ wih,
        const float* __restrict__ whh, const float* __restrict__ pl,
        const float* __restrict__ plr, const float* __restrict__ unif_x,
        const float* __restrict__ unif_h, _Float16* __restrict__ wih_h,
        _Float16* __restrict__ whh_h, _Float16* __restrict__ mask_x,
        _Float16* __restrict__ mask_h, float* __restrict__ partial) {
    int i = blockIdx.x * 256 + threadIdx.x;    // float4 index, 16384 total
    float4 a = ((const float4*)wih)[i];
    float4 b = ((const float4*)whh)[i];
    h4_t ah, bh;
    ah[0] = (_Float16)a.x; ah[1] = (_Float16)a.y; ah[2] = (_Float16)a.z; ah[3] = (_Float16)a.w;
    bh[0] = (_Float16)b.x; bh[1] = (_Float16)b.y; bh[2] = (_Float16)b.z; bh[3] = (_Float16)b.w;
    *(h4_t*)(wih_h + 4 * (size_t)i) = ah;
    *(h4_t*)(whh_h + 4 * (size_t)i) = bh;
    float sk = a.x * a.x + a.y * a.y + a.z * a.z + a.w * a.w;
    float sr = b.x * b.x + b.y * b.y + b.z * b.z + b.w * b.w;
    for (int off = 32; off; off >>= 1) {
        sk += __shfl_down(sk, off);
        sr += __shfl_down(sr, off);
    }
    if ((threadIdx.x & 63) == 0) {
        atomicAdd(partial + 0, sk);
        atomicAdd(partial + 1, sr);
    }
    // concrete-dropout masks: threads 0..8191 -> mask_x, 8192..16383 -> mask_h
    float p;
    const float* up;
    _Float16* mp;
    int mi;
    if (i < 8192) { p = sig(pl[0]);  up = unif_x; mp = mask_x; mi = i; }
    else          { p = sig(plr[0]); up = unif_h; mp = mask_h; mi = i - 8192; }
    float4 u = ((const float4*)up)[mi];
    float base = logf(p + F_EPS) - logf(1.f - p + F_EPS);
    float inv  = 1.f / (1.f - p);
    h4_t m4;
    {
        float uu[4] = {u.x, u.y, u.z, u.w};
#pragma unroll
        for (int e = 0; e < 4; ++e) {
            float lg = base + logf(uu[e] + F_EPS) - logf(1.f - uu[e] + F_EPS);
            float mk = 1.f - sig(lg / F_TEMP);
            m4[e] = (_Float16)(mk * inv);
        }
    }
    *(h4_t*)(mp + 4 * (size_t)mi) = m4;
}

// ---------------- kernel 1b: finalize scalar regularization outputs ----------------
__global__ void k_tail(const float* __restrict__ bih, const float* __restrict__ bhh,
                       const float* __restrict__ pl, const float* __restrict__ plr,
                       const float* __restrict__ partial, float* __restrict__ out_tail) {
    __shared__ float red[8];
    int t = threadIdx.x;  // 512 threads
    float v = bih[t], w2 = bhh[t];
    float sb = v * v + w2 * w2;
    for (int off = 32; off; off >>= 1) sb += __shfl_down(sb, off);
    int wid = t >> 6, lane = t & 63;
    if (lane == 0) red[wid] = sb;
    __syncthreads();
    if (t == 0) {
        float SB = 0.f;
        for (int i = 0; i < 8; i++) SB += red[i];
        float SK = partial[0], SR = partial[1];
        float p  = sig(pl[0]);
        float pr = sig(plr[0]);
        float wr = 1e-6f * (SK / (1.f - p) + SR / (1.f - pr));
        float br = 1e-6f * SB;
        float ek = p * logf(p) + (1.f - p) * logf(1.f - p);
        float er = pr * logf(pr) + (1.f - pr) * logf(1.f - pr);
        float dr = 1e-5f * ((float)ND * ek + (float)NH * er);
        out_tail[0] = wr + br + dr;
        out_tail[1] = p;
        out_tail[2] = pr;
    }
}

// ---------------- kernel 2: f16 MFMA input GEMM ----------------
// New G layout: G[((t*16 + (b>>4))*512 + j)*16 + (b&15)] — per-(t,bchunk) slab
// is 16KB CONTIGUOUS (fixes r9's DRAM row thrash: 512 rows x 256KB-apart).
// Store pattern per inst: 64 lanes cover a full contiguous 512B ✓.
__global__ __launch_bounds__(256, 2) void k_gemm(const float* __restrict__ x,
        const _Float16* __restrict__ wih_h, const float* __restrict__ bih,
        const float* __restrict__ bhh, const _Float16* __restrict__ mask_x,
        _Float16* __restrict__ Gp) {
    __shared__ _Float16 Alds[128 * 128];
    __shared__ _Float16 Wlds[128 * 128];
    __shared__ float bsum[128];
    int t  = threadIdx.x;
    int j0 = blockIdx.y * 128;           // gate-col block
    int tg  = blockIdx.x >> 1;           // timestep of this tile
    int b0g = (blockIdx.x & 1) * 128;    // batch base of this tile

    if (t < 128) bsum[t] = bih[j0 + t] + bhh[j0 + t];
    __syncthreads();

#pragma unroll
    for (int i = 0; i < 8; i++) {
        int s   = i * 256 + t;
        int row = s >> 4;                 // 0..127 (batch-local)
        int s16 = s & 15;                 // 16B slot within row
        int bb  = b0g + row;
        const float4* xp = (const float4*)(x + ((size_t)bb * NT + tg) * ND + s16 * 8);
        float4 v0 = xp[0], v1 = xp[1];
        h8_t mk = *(const h8_t*)(mask_x + (size_t)bb * ND + s16 * 8);
        h8_t hv;
        hv[0] = (_Float16)(v0.x * (float)mk[0]); hv[1] = (_Float16)(v0.y * (float)mk[1]);
        hv[2] = (_Float16)(v0.z * (float)mk[2]); hv[3] = (_Float16)(v0.w * (float)mk[3]);
        hv[4] = (_Float16)(v1.x * (float)mk[4]); hv[5] = (_Float16)(v1.y * (float)mk[5]);
        hv[6] = (_Float16)(v1.z * (float)mk[6]); hv[7] = (_Float16)(v1.w * (float)mk[7]);
        *(h8_t*)(&Alds[(size_t)row * 128 + ((s16 ^ (row & 7)) << 3)]) = hv;
        h8_t wv = *(const h8_t*)(wih_h + (size_t)(j0 + row) * ND + s16 * 8);
        *(h8_t*)(&Wlds[(size_t)row * 128 + ((s16 ^ (row & 7)) << 3)]) = wv;
    }
    __syncthreads();

    int w  = t >> 6, l = t & 63;
    int lr = l & 15, lg = l >> 4;
    fx4 acc[2][8] = {};
#pragma unroll
    for (int kk = 0; kk < 4; kk++) {
        h8_t af[2], bf[8];
#pragma unroll
        for (int mt = 0; mt < 2; mt++) {
            int r = 32 * w + 16 * mt + lr;
            af[mt] = *(const h8_t*)(&Alds[(size_t)r * 128 + (((4 * kk + lg) ^ (r & 7)) << 3)]);
        }
#pragma unroll
        for (int nt = 0; nt < 8; nt++) {
            int r = 16 * nt + lr;
            bf[nt] = *(const h8_t*)(&Wlds[(size_t)r * 128 + (((4 * kk + lg) ^ (r & 7)) << 3)]);
        }
#pragma unroll
        for (int mt = 0; mt < 2; mt++)
#pragma unroll
            for (int nt = 0; nt < 8; nt++)
                acc[mt][nt] = __builtin_amdgcn_mfma_f32_16x16x32_f16(af[mt], bf[nt], acc[mt][nt], 0, 0, 0);
    }

#pragma unroll
    for (int mt = 0; mt < 2; mt++)
#pragma unroll
        for (int nt = 0; nt < 8; nt++) {
            int j  = j0 + 16 * nt + lr;
            int bb = b0g + 32 * w + 16 * mt + 4 * lg;   // batch (4 consecutive via h4)
            float bv = bsum[16 * nt + lr];
            h4_t o;
#pragma unroll
            for (int q = 0; q < 4; q++) o[q] = (_Float16)(acc[mt][nt][q] + bv);
            size_t addr = (((size_t)tg * 16 + (bb >> 4)) * 512 + j) * 16 + (bb & 15);
            *(h4_t*)(Gp + addr) = o;
        }
}

// ---------------- kernel 3: MFMA recurrence, contiguous-G + 2-deep prefetch ---------
// 16 blocks x 16 batch rows, 512 threads (8 waves). Wave wv owns hidden units
// [16wv,16wv+16); its 4 n-tiles = the 4 GATES -> i,f,g,o of (batch m, unit u)
// land IN-LANE (r9-verified). W_hh in pinned B-fragments (64 VGPR). Per-step G
// slab is contiguous 16KB; every load inst is a coalesced 512B burst. Prefetch
// depth 2 (A/B register sets, 2-unrolled loop, static indices): ~2 steps
// (>1200cyc) of HBM latency budget. One LDS-only barrier/step.
__global__ __launch_bounds__(512, 1)
void k_lstm(const _Float16* __restrict__ Gp, const _Float16* __restrict__ whh_h,
            const _Float16* __restrict__ maskh,
            float* __restrict__ xout, float* __restrict__ hlast) {
    __shared__ _Float16 hd[2][LBLK * 128];
    int tid = threadIdx.x;
    int l   = tid & 63;
    int wv  = tid >> 6;            // 0..7
    int lr  = l & 15;              // A-row (batch) for reads / C-col (unit)
    int lq  = l >> 4;              // quarter
    int bc  = blockIdx.x;          // batch chunk 0..15
    int b0  = bc * LBLK;
    int u   = wv * 16 + lr;        // hidden unit owned

    // B-fragments: bf[g][kk] = W_hh[g*128+u][kk*32 + lq*8 .. +8)
    h8_t bf[4][4];
#pragma unroll
    for (int g = 0; g < 4; ++g)
#pragma unroll
        for (int kk = 0; kk < 4; ++kk)
            bf[g][kk] = *(const h8_t*)(whh_h + (size_t)(g * 128 + u) * NH + kk * 32 + lq * 8);

    float msk[4], c4[4], hl[4];
#pragma unroll
    for (int r = 0; r < 4; ++r) {
        msk[r] = (float)maskh[(size_t)(b0 + lq * 4 + r) * NH + u];
        c4[r] = 0.f; hl[r] = 0.f;
    }

    // G stream bases (t=0): slab-contiguous layout
    const _Float16* gp0 = Gp + ((size_t)bc * 512 + 0 * 128 + u) * 16 + lq * 4;
    const _Float16* gp1 = Gp + ((size_t)bc * 512 + 1 * 128 + u) * 16 + lq * 4;
    const _Float16* gp2 = Gp + ((size_t)bc * 512 + 2 * 128 + u) * 16 + lq * 4;
    const _Float16* gp3 = Gp + ((size_t)bc * 512 + 3 * 128 + u) * 16 + lq * 4;
    float* xo0 = xout + (size_t)(b0 + lq * 4 + 0) * NT * NH + u;
    float* xo1 = xout + (size_t)(b0 + lq * 4 + 1) * NT * NH + u;
    float* xo2 = xout + (size_t)(b0 + lq * 4 + 2) * NT * NH + u;
    float* xo3 = xout + (size_t)(b0 + lq * 4 + 3) * NT * NH + u;

    // zero-init hd parity 0 (h0 state)
    {
        char* h0 = (char*)&hd[0][0];
#pragma unroll
        for (int r = 0; r < 4; ++r) {
            int m = lq * 4 + r;
            *(_Float16*)(h0 + m * 256 + ((2 * u) ^ ((m & 7) << 4))) = (_Float16)0.f;
        }
    }

    // preload t=0 (set A) and t=1 (set B)
    h4_t A0 = *(const h4_t*)(gp0);
    h4_t A1 = *(const h4_t*)(gp1);
    h4_t A2 = *(const h4_t*)(gp2);
    h4_t A3 = *(const h4_t*)(gp3);
    h4_t B0 = *(const h4_t*)(gp0 + TSTR);
    h4_t B1 = *(const h4_t*)(gp1 + TSTR);
    h4_t B2 = *(const h4_t*)(gp2 + TSTR);
    h4_t B3 = *(const h4_t*)(gp3 + TSTR);
    __syncthreads();   // hd[0] init visible

    auto STEPF = [&](h4_t& GA0, h4_t& GA1, h4_t& GA2, h4_t& GA3,
                     int TT, int par) {
        // pin B-frags (prevent remat/spill of W_hh)
#pragma unroll
        for (int g = 0; g < 4; ++g)
#pragma unroll
            for (int kk = 0; kk < 4; ++kk) asm volatile("" : "+v"(bf[g][kk]));
        const char* hb = (const char*)&hd[par][0];
        fx4 a0 = {0.f, 0.f, 0.f, 0.f}, a1 = a0, a2 = a0, a3 = a0;
#pragma unroll
        for (int kk = 0; kk < 4; ++kk) {
            h8_t af = *(const h8_t*)(hb + lr * 256 + ((kk * 64 + lq * 16) ^ ((lr & 7) << 4)));
            a0 = __builtin_amdgcn_mfma_f32_16x16x32_f16(af, bf[0][kk], a0, 0, 0, 0);
            a1 = __builtin_amdgcn_mfma_f32_16x16x32_f16(af, bf[1][kk], a1, 0, 0, 0);
            a2 = __builtin_amdgcn_mfma_f32_16x16x32_f16(af, bf[2][kk], a2, 0, 0, 0);
            a3 = __builtin_amdgcn_mfma_f32_16x16x32_f16(af, bf[3][kk], a3, 0, 0, 0);
        }
        char* hw = (char*)&hd[par ^ 1][0];
#pragma unroll
        for (int r = 0; r < 4; ++r) {
            float si = a0[r] + (float)GA0[r];
            float sf = a1[r] + (float)GA1[r];
            float sg = a2[r] + (float)GA2[r];
            float so = a3[r] + (float)GA3[r];
            float iv = fsig(si), fv = fsig(sf);
            float gv = ftanh(sg), ov = fsig(so);
            c4[r] = fv * c4[r] + iv * gv;
            float h = ov * ftanh(c4[r]);
            hl[r] = h;
            int m = lq * 4 + r;
            *(_Float16*)(hw + m * 256 + ((2 * u) ^ ((m & 7) << 4))) = (_Float16)(h * msk[r]);
        }
        xo0[(size_t)TT * NH] = hl[0];   // vmem: never drained by bar_lds
        xo1[(size_t)TT * NH] = hl[1];
        xo2[(size_t)TT * NH] = hl[2];
        xo3[(size_t)TT * NH] = hl[3];
        // reload this set for TT+2 (consumed 2 steps from now -> latency hidden)
        int tn = TT + 2;
        if (tn >= NT) tn = NT - 1;
        GA0 = *(const h4_t*)(gp0 + (size_t)tn * TSTR);
        GA1 = *(const h4_t*)(gp1 + (size_t)tn * TSTR);
        GA2 = *(const h4_t*)(gp2 + (size_t)tn * TSTR);
        GA3 = *(const h4_t*)(gp3 + (size_t)tn * TSTR);
        bar_lds();   // hd writes visible; next step reads other parity
    };

    for (int t = 0; t < NT; t += 2) {
        STEPF(A0, A1, A2, A3, t, 0);
        STEPF(B0, B1, B2, B3, t + 1, 1);
    }
#pragma unroll
    for (int r = 0; r < 4; ++r)
        hlast[(size_t)(b0 + lq * 4 + r) * NH + u] = hl[r];
}

extern "C" void kernel_launch(void* const* d_in, const int* in_sizes, int n_in,
                              void* d_out, int out_size, void* d_ws, size_t ws_size,
                              hipStream_t stream) {
    const float* x   = (const float*)d_in[0];
    const float* wih = (const float*)d_in[1];
    const float* whh = (const float*)d_in[2];
    const float* bih = (const float*)d_in[3];
    const float* bhh = (const float*)d_in[4];
    const float* pl  = (const float*)d_in[5];
    const float* plr = (const float*)d_in[6];
    const float* ux  = (const float*)d_in[7];
    const float* uh  = (const float*)d_in[8];

    float* out   = (float*)d_out;
    float* xout  = out;                                 // [B,T,H]
    float* hlast = out + (size_t)NB * NT * NH;          // [B,H]
    float* tail  = hlast + (size_t)NB * NH;             // reg, p, p_rec

    _Float16* G      = (_Float16*)d_ws;                 // slab layout, fits in NG*NMP
    _Float16* wih_h  = G + (size_t)NG * NMP;
    _Float16* whh_h  = wih_h + (size_t)NG * ND;
    _Float16* mask_x = whh_h + (size_t)NG * NH;         // [NB][ND] f16 (incl /(1-p))
    _Float16* mask_h = mask_x + (size_t)NB * ND;        // [NB][NH] f16 (incl /(1-pr))
    float*    partial = (float*)(mask_h + (size_t)NB * NH);   // 2 floats

    hipMemsetAsync(partial, 0, 2 * sizeof(float), stream);

    k_convert<<<64, 256, 0, stream>>>(wih, whh, pl, plr, ux, uh,
                                      wih_h, whh_h, mask_x, mask_h, partial);

    dim3 gg(NM / 128, NG / 128);
    k_gemm<<<gg, 256, 0, stream>>>(x, wih_h, bih, bhh, mask_x, G);

    k_tail<<<1, 512, 0, stream>>>(bih, bhh, pl, plr, partial, tail);

    k_lstm<<<NB / LBLK, 512, 0, stream>>>(G, whh_h, mask_h, xout, hlast);
}